// Round 1
// baseline (37603.174 us; speedup 1.0000x reference)
//
#include <hip/hip_runtime.h>
#include <cstdint>
#include <cstddef>

#define BATCHN 8
#define TLEN   3200
#define NCH    512     // encoder feats
#define BCH    128     // bottleneck
#define HCH    512     // hidden
#define LBLK   24
#define CNTF   (512.0f * 3200.0f)
#define EPSV   1e-8f

// input-transform modes (applied when loading X tile)
enum { XF_NONE = 0, XF_GLN = 1, XF_PRELU = 2 };
// epilogue modes
enum { EP_STORE = 0, EP_PRELU_STATS = 1, EP_DUAL = 2, EP_SIGMOID = 3 };

__device__ inline void block_reduce_atomic2(float s, float ss, float* out) {
#pragma unroll
    for (int off = 32; off; off >>= 1) {
        s  += __shfl_down(s, off, 64);
        ss += __shfl_down(ss, off, 64);
    }
    __shared__ float pr[8];
    const int wave = threadIdx.x >> 6;
    const int lane = threadIdx.x & 63;
    if (lane == 0) { pr[wave * 2] = s; pr[wave * 2 + 1] = ss; }
    __syncthreads();
    if (threadIdx.x == 0) {
        const int nw = blockDim.x >> 6;
        float a = 0.f, b = 0.f;
        for (int i = 0; i < nw; i++) { a += pr[i * 2]; b += pr[i * 2 + 1]; }
        atomicAdd(out, a);
        atomicAdd(out + 1, b);
    }
}

// Generic fp32 GEMM: Y[b] = A(MxK) @ X[b](KxT) + bias, with optional input
// transform (gLN / PReLU folded into the X load) and fused epilogues.
// Tiles: 64(M) x 64(T), 256 threads, 4x4 micro-tile, K-chunk 16 via LDS.
template <int XF, int EP>
__global__ __launch_bounds__(256, 2) void gemm_k(
    const float* __restrict__ A, const float* __restrict__ A2,
    const float* __restrict__ bias, const float* __restrict__ bias2,
    const float* __restrict__ Xin, float* __restrict__ Y, float* __restrict__ Y2,
    const float* __restrict__ gamma, const float* __restrict__ beta,
    const float* __restrict__ statsIn, float* __restrict__ statsOut,
    const float* __restrict__ alphaPtr, int M, int K)
{
    const int b   = blockIdx.z;
    const int t0  = blockIdx.x * 64;
    const int m0  = blockIdx.y * 64;
    const int tid = threadIdx.x;

    const float* Ause   = A;
    const float* biasUse = bias;
    int  mbase = m0;
    bool isRes = false;
    if (EP == EP_DUAL && m0 >= BCH) {
        Ause = A2; biasUse = bias2; mbase = m0 - BCH; isRes = true;
    }

    float mean = 0.f, rstd = 1.f, alpha = 0.f;
    if (XF == XF_GLN) {
        const float s  = statsIn[b * 2 + 0];
        const float ss = statsIn[b * 2 + 1];
        const float mu = s * (1.f / CNTF);
        const float var = ss * (1.f / CNTF) - mu * mu;
        mean = mu;
        rstd = rsqrtf(var + EPSV);
    }
    if (XF == XF_PRELU || EP == EP_PRELU_STATS) alpha = alphaPtr[0];

    __shared__ __align__(16) float As[16][68];
    __shared__ __align__(16) float Bs[16][68];

    float acc[4][4];
#pragma unroll
    for (int i = 0; i < 4; i++)
#pragma unroll
        for (int j = 0; j < 4; j++) acc[i][j] = 0.f;

    const int arow = tid >> 2;         // 0..63  (m within tile)
    const int acol = (tid & 3) * 4;    // 0,4,8,12 (k within chunk)
    const int brow = tid >> 4;         // 0..15  (k within chunk)
    const int bcol = (tid & 15) * 4;   // 0..60  (t within tile)

    const float* Arow = Ause + (size_t)(mbase + arow) * K;
    const float* Xrow = Xin + ((size_t)b * K + brow) * (size_t)TLEN + t0 + bcol;

    const int ty = tid >> 4;   // 0..15 (m micro)
    const int tx = tid & 15;   // 0..15 (t micro)

    for (int k0 = 0; k0 < K; k0 += 16) {
        float4 av = *reinterpret_cast<const float4*>(Arow + k0 + acol);
        float4 bv = *reinterpret_cast<const float4*>(Xrow + (size_t)k0 * TLEN);
        if (XF == XF_GLN) {
            const int ch = k0 + brow;
            const float g  = gamma[ch] * rstd;
            const float be = beta[ch] - mean * rstd * gamma[ch];
            bv.x = bv.x * g + be; bv.y = bv.y * g + be;
            bv.z = bv.z * g + be; bv.w = bv.w * g + be;
        } else if (XF == XF_PRELU) {
            bv.x = bv.x >= 0.f ? bv.x : alpha * bv.x;
            bv.y = bv.y >= 0.f ? bv.y : alpha * bv.y;
            bv.z = bv.z >= 0.f ? bv.z : alpha * bv.z;
            bv.w = bv.w >= 0.f ? bv.w : alpha * bv.w;
        }
        As[acol + 0][arow] = av.x;
        As[acol + 1][arow] = av.y;
        As[acol + 2][arow] = av.z;
        As[acol + 3][arow] = av.w;
        *reinterpret_cast<float4*>(&Bs[brow][bcol]) = bv;
        __syncthreads();
#pragma unroll
        for (int kk = 0; kk < 16; kk++) {
            const float4 a4 = *reinterpret_cast<const float4*>(&As[kk][ty << 2]);
            const float4 b4 = *reinterpret_cast<const float4*>(&Bs[kk][tx << 2]);
            const float aa[4] = { a4.x, a4.y, a4.z, a4.w };
            const float bb[4] = { b4.x, b4.y, b4.z, b4.w };
#pragma unroll
            for (int i = 0; i < 4; i++)
#pragma unroll
                for (int j = 0; j < 4; j++) acc[i][j] += aa[i] * bb[j];
        }
        __syncthreads();
    }

    float ssum = 0.f, ssq = 0.f;
#pragma unroll
    for (int i = 0; i < 4; i++) {
        const int mloc = mbase + (ty << 2) + i;      // row within A / target
        const float bz = biasUse[mloc];
        float4 r4;
        r4.x = acc[i][0] + bz;
        r4.y = acc[i][1] + bz;
        r4.z = acc[i][2] + bz;
        r4.w = acc[i][3] + bz;
        const int t = t0 + (tx << 2);
        if (EP == EP_STORE) {
            *reinterpret_cast<float4*>(&Y[((size_t)b * M + mloc) * TLEN + t]) = r4;
        } else if (EP == EP_PRELU_STATS) {
            r4.x = r4.x >= 0.f ? r4.x : alpha * r4.x;
            r4.y = r4.y >= 0.f ? r4.y : alpha * r4.y;
            r4.z = r4.z >= 0.f ? r4.z : alpha * r4.z;
            r4.w = r4.w >= 0.f ? r4.w : alpha * r4.w;
            *reinterpret_cast<float4*>(&Y[((size_t)b * M + mloc) * TLEN + t]) = r4;
            ssum += r4.x + r4.y + r4.z + r4.w;
            ssq  += r4.x * r4.x + r4.y * r4.y + r4.z * r4.z + r4.w * r4.w;
        } else if (EP == EP_DUAL) {
            float* tgt = isRes ? Y2 : Y;
            float4* p = reinterpret_cast<float4*>(&tgt[((size_t)b * BCH + mloc) * TLEN + t]);
            float4 old = *p;
            old.x += r4.x; old.y += r4.y; old.z += r4.z; old.w += r4.w;
            *p = old;
        } else { // EP_SIGMOID
            r4.x = 1.f / (1.f + expf(-r4.x));
            r4.y = 1.f / (1.f + expf(-r4.y));
            r4.z = 1.f / (1.f + expf(-r4.z));
            r4.w = 1.f / (1.f + expf(-r4.w));
            *reinterpret_cast<float4*>(&Y[((size_t)b * M + mloc) * TLEN + t]) = r4;
        }
    }
    if (EP == EP_PRELU_STATS) block_reduce_atomic2(ssum, ssq, statsOut + b * 2);
}

// Depthwise dilated conv (K=3) with gLN(g1,be1) folded into the input load,
// +bias, PReLU(a2), and fused stats accumulation for the following gLN.
__global__ __launch_bounds__(256) void dwconv_k(
    const float* __restrict__ h, float* __restrict__ hd,
    const float* __restrict__ Wd, const float* __restrict__ bd,
    const float* __restrict__ g1, const float* __restrict__ be1,
    const float* __restrict__ statsIn, float* __restrict__ statsOut,
    const float* __restrict__ a2p, int dil)
{
    const int b  = blockIdx.z;
    const int ch = blockIdx.y;
    const int t  = blockIdx.x * 256 + threadIdx.x;

    const float s  = statsIn[b * 2 + 0];
    const float ss = statsIn[b * 2 + 1];
    const float mu = s * (1.f / CNTF);
    const float var = ss * (1.f / CNTF) - mu * mu;
    const float rstd = rsqrtf(var + EPSV);
    const float g  = g1[ch] * rstd;
    const float be = be1[ch] - mu * rstd * g1[ch];
    const float w0 = Wd[ch * 3 + 0];
    const float w1 = Wd[ch * 3 + 1];
    const float w2 = Wd[ch * 3 + 2];
    const float alpha = a2p[0];

    const float* row = h + ((size_t)b * HCH + ch) * TLEN;
    float v = 0.f;
    if (t < TLEN) {
        float acc = bd[ch];
        if (t - dil >= 0)  acc += w0 * (row[t - dil] * g + be);
        acc += w1 * (row[t] * g + be);
        if (t + dil < TLEN) acc += w2 * (row[t + dil] * g + be);
        v = acc >= 0.f ? acc : alpha * acc;
        hd[((size_t)b * HCH + ch) * TLEN + t] = v;
    }
    block_reduce_atomic2(v, v * v, statsOut + b * 2);
}

// Stats (sum, sumsq) of raw input x per sample over (N, T).
__global__ __launch_bounds__(256) void stats_x_k(
    const float* __restrict__ x, float* __restrict__ statsOut)
{
    const int b = blockIdx.y;
    const float* base = x + (size_t)b * (NCH * TLEN) + (size_t)blockIdx.x * 16384;
    float s = 0.f, ss = 0.f;
#pragma unroll
    for (int i = 0; i < 16; i++) {
        const float4 v = *reinterpret_cast<const float4*>(base + i * 1024 + threadIdx.x * 4);
        s  += v.x + v.y + v.z + v.w;
        ss += v.x * v.x + v.y * v.y + v.z * v.z + v.w * v.w;
    }
    block_reduce_atomic2(s, ss, statsOut + b * 2);
}

extern "C" void kernel_launch(void* const* d_in, const int* in_sizes, int n_in,
                              void* d_out, int out_size, void* d_ws, size_t ws_size,
                              hipStream_t stream)
{
    (void)in_sizes; (void)n_in; (void)out_size; (void)ws_size;

    const float* x    = (const float*)d_in[0];
    const float* in_g = (const float*)d_in[1];
    const float* in_b = (const float*)d_in[2];
    const float* Wc   = (const float*)d_in[3];
    const float* bc   = (const float*)d_in[4];
    const float* W1   = (const float*)d_in[5];
    const float* b1   = (const float*)d_in[6];
    const float* a1   = (const float*)d_in[7];
    const float* g1   = (const float*)d_in[8];
    const float* be1  = (const float*)d_in[9];
    const float* Wd   = (const float*)d_in[10];
    const float* bd   = (const float*)d_in[11];
    const float* a2   = (const float*)d_in[12];
    const float* g2   = (const float*)d_in[13];
    const float* be2  = (const float*)d_in[14];
    const float* Wres = (const float*)d_in[15];
    const float* bres = (const float*)d_in[16];
    const float* Wskip= (const float*)d_in[17];
    const float* bskip= (const float*)d_in[18];
    const float* aout = (const float*)d_in[19];
    const float* Wo   = (const float*)d_in[20];
    const float* bo   = (const float*)d_in[21];
    float* out = (float*)d_out;

    float* ws = (float*)d_ws;
    const size_t featsN = (size_t)BATCHN * BCH * TLEN;   // 3,276,800 floats
    const size_t hN     = (size_t)BATCHN * HCH * TLEN;   // 13,107,200 floats
    float* feats  = ws;
    float* outAcc = feats + featsN;
    float* h      = outAcc + featsN;
    float* hd     = h + hN;
    float* stats  = hd + hN;                             // 49 slots * 8 * 2 floats

    hipMemsetAsync(stats, 0, (size_t)49 * BATCHN * 2 * sizeof(float), stream);
    hipMemsetAsync(outAcc, 0, featsN * sizeof(float), stream);

    const dim3 blk(256);

    // input gLN stats
    stats_x_k<<<dim3(100, BATCHN), blk, 0, stream>>>(x, stats);

    // feats = Wc @ gln(x) + bc
    gemm_k<XF_GLN, EP_STORE><<<dim3(50, BCH / 64, BATCHN), blk, 0, stream>>>(
        Wc, nullptr, bc, nullptr, x, feats, nullptr, in_g, in_b,
        stats, nullptr, nullptr, BCH, NCH);

    for (int i = 0; i < LBLK; i++) {
        const int dil = 1 << (i & 7);
        float* st_h  = stats + (size_t)(1 + 2 * i) * BATCHN * 2;
        float* st_hd = stats + (size_t)(2 + 2 * i) * BATCHN * 2;

        // h = PReLU(W1 @ feats + b1, a1); accumulate stats(h)
        gemm_k<XF_NONE, EP_PRELU_STATS><<<dim3(50, HCH / 64, BATCHN), blk, 0, stream>>>(
            W1 + (size_t)i * HCH * BCH, nullptr, b1 + (size_t)i * HCH, nullptr,
            feats, h, nullptr, nullptr, nullptr, nullptr, st_h, a1 + i, HCH, BCH);

        // hd = PReLU(dwconv(gln(h)) + bd, a2); accumulate stats(hd)
        dwconv_k<<<dim3(13, HCH, BATCHN), blk, 0, stream>>>(
            h, hd, Wd + (size_t)i * HCH * 3, bd + (size_t)i * HCH,
            g1 + (size_t)i * HCH, be1 + (size_t)i * HCH, st_h, st_hd, a2 + i, dil);

        // outAcc += Wskip @ gln(hd) + bskip ; feats += Wres @ gln(hd) + bres
        const int mtiles = (i < LBLK - 1) ? (2 * BCH) / 64 : BCH / 64; // last: skip only
        gemm_k<XF_GLN, EP_DUAL><<<dim3(50, mtiles, BATCHN), blk, 0, stream>>>(
            Wskip + (size_t)i * BCH * HCH, Wres + (size_t)i * BCH * HCH,
            bskip + (size_t)i * BCH, bres + (size_t)i * BCH,
            hd, outAcc, feats, g2 + (size_t)i * HCH, be2 + (size_t)i * HCH,
            st_hd, nullptr, nullptr, 2 * BCH, HCH);
    }

    // out = sigmoid(Wo @ PReLU(outAcc, a_out) + bo)
    gemm_k<XF_PRELU, EP_SIGMOID><<<dim3(50, (2 * NCH) / 64, BATCHN), blk, 0, stream>>>(
        Wo, nullptr, bo, nullptr, outAcc, out, nullptr, nullptr, nullptr,
        nullptr, nullptr, aout, 2 * NCH, BCH);
}

// Round 2
// 5016.503 us; speedup vs baseline: 7.4959x; 7.4959x over previous
//
#include <hip/hip_runtime.h>
#include <cstdint>
#include <cstddef>

#define BATCHN 8
#define TLEN   3200
#define NCH    512     // encoder feats
#define BCH    128     // bottleneck
#define HCH    512     // hidden
#define LBLK   24
#define CNTF   (512.0f * 3200.0f)
#define EPSV   1e-8f
#define NSLOT  32      // stats spread slots per sample (atomic decontention)

// input-transform modes (applied when loading X tile)
enum { XF_NONE = 0, XF_GLN = 1, XF_PRELU = 2 };
// epilogue modes
enum { EP_STORE = 0, EP_PRELU_STATS = 1, EP_DUAL = 2, EP_SIGMOID = 3 };

__device__ inline void block_reduce_atomic2(float s, float ss, float* out) {
#pragma unroll
    for (int off = 32; off; off >>= 1) {
        s  += __shfl_down(s, off, 64);
        ss += __shfl_down(ss, off, 64);
    }
    __shared__ float pr[8];
    const int wave = threadIdx.x >> 6;
    const int lane = threadIdx.x & 63;
    if (lane == 0) { pr[wave * 2] = s; pr[wave * 2 + 1] = ss; }
    __syncthreads();
    if (threadIdx.x == 0) {
        const int nw = blockDim.x >> 6;
        float a = 0.f, b = 0.f;
        for (int i = 0; i < nw; i++) { a += pr[i * 2]; b += pr[i * 2 + 1]; }
        atomicAdd(out, a);
        atomicAdd(out + 1, b);
    }
}

// Sum the 32 spread stat slots for sample b -> mean, rstd.
__device__ inline void load_stats32(const float* __restrict__ st,
                                    float& mu, float& rstd) {
    float s = 0.f, ss = 0.f;
#pragma unroll
    for (int i = 0; i < NSLOT; i++) { s += st[2 * i]; ss += st[2 * i + 1]; }
    mu = s * (1.f / CNTF);
    const float var = ss * (1.f / CNTF) - mu * mu;
    rstd = rsqrtf(var + EPSV);
}

// Generic fp32 GEMM: Y[b] = A(MxK) @ X[b](KxT) + bias, with optional input
// transform (gLN / PReLU folded into the X load) and fused epilogues.
// Tiles: 64(M) x 64(T), 256 threads, 4x4 micro-tile, K-chunk 16 via LDS.
template <int XF, int EP>
__global__ __launch_bounds__(256, 2) void gemm_k(
    const float* __restrict__ A, const float* __restrict__ A2,
    const float* __restrict__ bias, const float* __restrict__ bias2,
    const float* __restrict__ Xin, float* __restrict__ Y, float* __restrict__ Y2,
    const float* __restrict__ gamma, const float* __restrict__ beta,
    const float* __restrict__ statsIn, float* __restrict__ statsOut,
    const float* __restrict__ alphaPtr, int M, int K)
{
    const int b   = blockIdx.z;
    const int t0  = blockIdx.x * 64;
    const int m0  = blockIdx.y * 64;
    const int tid = threadIdx.x;

    const float* Ause   = A;
    const float* biasUse = bias;
    int  mbase = m0;
    bool isRes = false;
    if (EP == EP_DUAL && m0 >= BCH) {
        Ause = A2; biasUse = bias2; mbase = m0 - BCH; isRes = true;
    }

    float mean = 0.f, rstd = 1.f, alpha = 0.f;
    if (XF == XF_GLN) load_stats32(statsIn + b * (2 * NSLOT), mean, rstd);
    if (XF == XF_PRELU || EP == EP_PRELU_STATS) alpha = alphaPtr[0];

    __shared__ __align__(16) float As[16][68];
    __shared__ __align__(16) float Bs[16][68];

    float acc[4][4];
#pragma unroll
    for (int i = 0; i < 4; i++)
#pragma unroll
        for (int j = 0; j < 4; j++) acc[i][j] = 0.f;

    const int arow = tid >> 2;         // 0..63  (m within tile)
    const int acol = (tid & 3) * 4;    // 0,4,8,12 (k within chunk)
    const int brow = tid >> 4;         // 0..15  (k within chunk)
    const int bcol = (tid & 15) * 4;   // 0..60  (t within tile)

    const float* Arow = Ause + (size_t)(mbase + arow) * K;
    const float* Xrow = Xin + ((size_t)b * K + brow) * (size_t)TLEN + t0 + bcol;

    const int ty = tid >> 4;   // 0..15 (m micro)
    const int tx = tid & 15;   // 0..15 (t micro)

    for (int k0 = 0; k0 < K; k0 += 16) {
        float4 av = *reinterpret_cast<const float4*>(Arow + k0 + acol);
        float4 bv = *reinterpret_cast<const float4*>(Xrow + (size_t)k0 * TLEN);
        if (XF == XF_GLN) {
            const int ch = k0 + brow;
            const float g  = gamma[ch] * rstd;
            const float be = beta[ch] - mean * rstd * gamma[ch];
            bv.x = bv.x * g + be; bv.y = bv.y * g + be;
            bv.z = bv.z * g + be; bv.w = bv.w * g + be;
        } else if (XF == XF_PRELU) {
            bv.x = bv.x >= 0.f ? bv.x : alpha * bv.x;
            bv.y = bv.y >= 0.f ? bv.y : alpha * bv.y;
            bv.z = bv.z >= 0.f ? bv.z : alpha * bv.z;
            bv.w = bv.w >= 0.f ? bv.w : alpha * bv.w;
        }
        As[acol + 0][arow] = av.x;
        As[acol + 1][arow] = av.y;
        As[acol + 2][arow] = av.z;
        As[acol + 3][arow] = av.w;
        *reinterpret_cast<float4*>(&Bs[brow][bcol]) = bv;
        __syncthreads();
#pragma unroll
        for (int kk = 0; kk < 16; kk++) {
            const float4 a4 = *reinterpret_cast<const float4*>(&As[kk][ty << 2]);
            const float4 b4 = *reinterpret_cast<const float4*>(&Bs[kk][tx << 2]);
            const float aa[4] = { a4.x, a4.y, a4.z, a4.w };
            const float bb[4] = { b4.x, b4.y, b4.z, b4.w };
#pragma unroll
            for (int i = 0; i < 4; i++)
#pragma unroll
                for (int j = 0; j < 4; j++) acc[i][j] += aa[i] * bb[j];
        }
        __syncthreads();
    }

    float ssum = 0.f, ssq = 0.f;
#pragma unroll
    for (int i = 0; i < 4; i++) {
        const int mloc = mbase + (ty << 2) + i;      // row within A / target
        const float bz = biasUse[mloc];
        float4 r4;
        r4.x = acc[i][0] + bz;
        r4.y = acc[i][1] + bz;
        r4.z = acc[i][2] + bz;
        r4.w = acc[i][3] + bz;
        const int t = t0 + (tx << 2);
        if (EP == EP_STORE) {
            *reinterpret_cast<float4*>(&Y[((size_t)b * M + mloc) * TLEN + t]) = r4;
        } else if (EP == EP_PRELU_STATS) {
            r4.x = r4.x >= 0.f ? r4.x : alpha * r4.x;
            r4.y = r4.y >= 0.f ? r4.y : alpha * r4.y;
            r4.z = r4.z >= 0.f ? r4.z : alpha * r4.z;
            r4.w = r4.w >= 0.f ? r4.w : alpha * r4.w;
            *reinterpret_cast<float4*>(&Y[((size_t)b * M + mloc) * TLEN + t]) = r4;
            ssum += r4.x + r4.y + r4.z + r4.w;
            ssq  += r4.x * r4.x + r4.y * r4.y + r4.z * r4.z + r4.w * r4.w;
        } else if (EP == EP_DUAL) {
            float* tgt = isRes ? Y2 : Y;
            float4* p = reinterpret_cast<float4*>(&tgt[((size_t)b * BCH + mloc) * TLEN + t]);
            float4 old = *p;
            old.x += r4.x; old.y += r4.y; old.z += r4.z; old.w += r4.w;
            *p = old;
        } else { // EP_SIGMOID
            r4.x = 1.f / (1.f + expf(-r4.x));
            r4.y = 1.f / (1.f + expf(-r4.y));
            r4.z = 1.f / (1.f + expf(-r4.z));
            r4.w = 1.f / (1.f + expf(-r4.w));
            *reinterpret_cast<float4*>(&Y[((size_t)b * M + mloc) * TLEN + t]) = r4;
        }
    }
    if (EP == EP_PRELU_STATS)
        block_reduce_atomic2(ssum, ssq,
            statsOut + b * (2 * NSLOT) + (blockIdx.x & (NSLOT - 1)) * 2);
}

// Depthwise dilated conv (K=3): one block per (channel, sample) row.
// gLN(g1,be1) folded into the LDS staging load, then conv + bias + PReLU(a2)
// computed from LDS, with one spread-slot stats atomic per block.
__global__ __launch_bounds__(256) void dwconv_k(
    const float* __restrict__ h, float* __restrict__ hd,
    const float* __restrict__ Wd, const float* __restrict__ bd,
    const float* __restrict__ g1, const float* __restrict__ be1,
    const float* __restrict__ statsIn, float* __restrict__ statsOut,
    const float* __restrict__ a2p, int dil)
{
    const int ch = blockIdx.x;
    const int b  = blockIdx.y;

    float mu, rstd;
    load_stats32(statsIn + b * (2 * NSLOT), mu, rstd);
    const float g  = g1[ch] * rstd;
    const float be = be1[ch] - mu * rstd * g1[ch];
    const float w0 = Wd[ch * 3 + 0];
    const float w1 = Wd[ch * 3 + 1];
    const float w2 = Wd[ch * 3 + 2];
    const float bz = bd[ch];
    const float alpha = a2p[0];

    __shared__ __align__(16) float row_s[TLEN];

    const float* __restrict__ row = h + ((size_t)b * HCH + ch) * TLEN;
    float*       __restrict__ orow = hd + ((size_t)b * HCH + ch) * TLEN;

    // Stage gLN-transformed row into LDS (800 float4s over 256 threads).
    for (int i = threadIdx.x; i < TLEN / 4; i += 256) {
        float4 v = reinterpret_cast<const float4*>(row)[i];
        v.x = v.x * g + be; v.y = v.y * g + be;
        v.z = v.z * g + be; v.w = v.w * g + be;
        reinterpret_cast<float4*>(row_s)[i] = v;
    }
    __syncthreads();

    float psum = 0.f, psq = 0.f;
    for (int i = threadIdx.x; i < TLEN / 4; i += 256) {
        const int t = i * 4;
        float4 o;
        float* op = &o.x;
#pragma unroll
        for (int j = 0; j < 4; j++) {
            const int tt = t + j;
            float acc = bz + w1 * row_s[tt];
            if (tt - dil >= 0)   acc += w0 * row_s[tt - dil];
            if (tt + dil < TLEN) acc += w2 * row_s[tt + dil];
            const float v = acc >= 0.f ? acc : alpha * acc;
            op[j] = v;
            psum += v;
            psq  += v * v;
        }
        reinterpret_cast<float4*>(orow)[i] = o;
    }
    block_reduce_atomic2(psum, psq,
        statsOut + b * (2 * NSLOT) + (ch & (NSLOT - 1)) * 2);
}

// Stats (sum, sumsq) of raw input x per sample over (N, T).
__global__ __launch_bounds__(256) void stats_x_k(
    const float* __restrict__ x, float* __restrict__ statsOut)
{
    const int b = blockIdx.y;
    const float* base = x + (size_t)b * (NCH * TLEN) + (size_t)blockIdx.x * 16384;
    float s = 0.f, ss = 0.f;
#pragma unroll
    for (int i = 0; i < 16; i++) {
        const float4 v = *reinterpret_cast<const float4*>(base + i * 1024 + threadIdx.x * 4);
        s  += v.x + v.y + v.z + v.w;
        ss += v.x * v.x + v.y * v.y + v.z * v.z + v.w * v.w;
    }
    block_reduce_atomic2(s, ss,
        statsOut + b * (2 * NSLOT) + (blockIdx.x & (NSLOT - 1)) * 2);
}

extern "C" void kernel_launch(void* const* d_in, const int* in_sizes, int n_in,
                              void* d_out, int out_size, void* d_ws, size_t ws_size,
                              hipStream_t stream)
{
    (void)in_sizes; (void)n_in; (void)out_size; (void)ws_size;

    const float* x    = (const float*)d_in[0];
    const float* in_g = (const float*)d_in[1];
    const float* in_b = (const float*)d_in[2];
    const float* Wc   = (const float*)d_in[3];
    const float* bc   = (const float*)d_in[4];
    const float* W1   = (const float*)d_in[5];
    const float* b1   = (const float*)d_in[6];
    const float* a1   = (const float*)d_in[7];
    const float* g1   = (const float*)d_in[8];
    const float* be1  = (const float*)d_in[9];
    const float* Wd   = (const float*)d_in[10];
    const float* bd   = (const float*)d_in[11];
    const float* a2   = (const float*)d_in[12];
    const float* g2   = (const float*)d_in[13];
    const float* be2  = (const float*)d_in[14];
    const float* Wres = (const float*)d_in[15];
    const float* bres = (const float*)d_in[16];
    const float* Wskip= (const float*)d_in[17];
    const float* bskip= (const float*)d_in[18];
    const float* aout = (const float*)d_in[19];
    const float* Wo   = (const float*)d_in[20];
    const float* bo   = (const float*)d_in[21];
    float* out = (float*)d_out;

    float* ws = (float*)d_ws;
    const size_t featsN = (size_t)BATCHN * BCH * TLEN;   // 3,276,800 floats
    const size_t hN     = (size_t)BATCHN * HCH * TLEN;   // 13,107,200 floats
    float* feats  = ws;
    float* outAcc = feats + featsN;
    float* h      = outAcc + featsN;
    float* hd     = h + hN;
    float* stats  = hd + hN;    // 49 stat slots, each [BATCHN][NSLOT][2] floats

    const size_t statSlot = (size_t)BATCHN * 2 * NSLOT;  // floats per stat slot

    hipMemsetAsync(stats, 0, (size_t)49 * statSlot * sizeof(float), stream);
    hipMemsetAsync(outAcc, 0, featsN * sizeof(float), stream);

    const dim3 blk(256);

    // input gLN stats
    stats_x_k<<<dim3(100, BATCHN), blk, 0, stream>>>(x, stats);

    // feats = Wc @ gln(x) + bc
    gemm_k<XF_GLN, EP_STORE><<<dim3(50, BCH / 64, BATCHN), blk, 0, stream>>>(
        Wc, nullptr, bc, nullptr, x, feats, nullptr, in_g, in_b,
        stats, nullptr, nullptr, BCH, NCH);

    for (int i = 0; i < LBLK; i++) {
        const int dil = 1 << (i & 7);
        float* st_h  = stats + (size_t)(1 + 2 * i) * statSlot;
        float* st_hd = stats + (size_t)(2 + 2 * i) * statSlot;

        // h = PReLU(W1 @ feats + b1, a1); accumulate stats(h)
        gemm_k<XF_NONE, EP_PRELU_STATS><<<dim3(50, HCH / 64, BATCHN), blk, 0, stream>>>(
            W1 + (size_t)i * HCH * BCH, nullptr, b1 + (size_t)i * HCH, nullptr,
            feats, h, nullptr, nullptr, nullptr, nullptr, st_h, a1 + i, HCH, BCH);

        // hd = PReLU(dwconv(gln(h)) + bd, a2); accumulate stats(hd)
        dwconv_k<<<dim3(HCH, BATCHN), blk, 0, stream>>>(
            h, hd, Wd + (size_t)i * HCH * 3, bd + (size_t)i * HCH,
            g1 + (size_t)i * HCH, be1 + (size_t)i * HCH, st_h, st_hd, a2 + i, dil);

        // outAcc += Wskip @ gln(hd) + bskip ; feats += Wres @ gln(hd) + bres
        const int mtiles = (i < LBLK - 1) ? (2 * BCH) / 64 : BCH / 64; // last: skip only
        gemm_k<XF_GLN, EP_DUAL><<<dim3(50, mtiles, BATCHN), blk, 0, stream>>>(
            Wskip + (size_t)i * BCH * HCH, Wres + (size_t)i * BCH * HCH,
            bskip + (size_t)i * BCH, bres + (size_t)i * BCH,
            hd, outAcc, feats, g2 + (size_t)i * HCH, be2 + (size_t)i * HCH,
            st_hd, nullptr, nullptr, 2 * BCH, HCH);
    }

    // out = sigmoid(Wo @ PReLU(outAcc, a_out) + bo)
    gemm_k<XF_PRELU, EP_SIGMOID><<<dim3(50, (2 * NCH) / 64, BATCHN), blk, 0, stream>>>(
        Wo, nullptr, bo, nullptr, outAcc, out, nullptr, nullptr, nullptr,
        nullptr, nullptr, aout, 2 * NCH, BCH);
}

// Round 3
// 2768.584 us; speedup vs baseline: 13.5821x; 1.8119x over previous
//
#include <hip/hip_runtime.h>
#include <cstdint>
#include <cstddef>

#define BATCHN 8
#define TLEN   3200
#define NCH    512
#define BCH    128
#define HCH    512
#define LBLK   24
#define CNTF   (512.0f * 3200.0f)
#define EPSV   1e-8f
#define NSLOT  32

typedef float  floatx4 __attribute__((ext_vector_type(4)));
typedef short  short8  __attribute__((ext_vector_type(8)));
typedef short  short4v __attribute__((ext_vector_type(4)));

enum { EP_H = 0, EP_FIRST = 1, EP_DUAL = 2 };

__device__ inline unsigned short f2bf(float f) {
    unsigned int u = __float_as_uint(f);
    u = (u + 0x7fffu + ((u >> 16) & 1u)) >> 16;
    return (unsigned short)u;
}
__device__ inline float bf2f(short s) {
    return __uint_as_float(((unsigned int)(unsigned short)s) << 16);
}

__device__ inline void block_reduce_atomic2(float s, float ss, float* out) {
#pragma unroll
    for (int off = 32; off; off >>= 1) {
        s  += __shfl_down(s, off, 64);
        ss += __shfl_down(ss, off, 64);
    }
    __shared__ float pr[8];
    const int wave = threadIdx.x >> 6;
    const int lane = threadIdx.x & 63;
    if (lane == 0) { pr[wave * 2] = s; pr[wave * 2 + 1] = ss; }
    __syncthreads();
    if (threadIdx.x == 0) {
        const int nw = blockDim.x >> 6;
        float a = 0.f, b = 0.f;
        for (int i = 0; i < nw; i++) { a += pr[i * 2]; b += pr[i * 2 + 1]; }
        atomicAdd(out, a);
        atomicAdd(out + 1, b);
    }
}

__device__ inline void load_stats32(const float* __restrict__ st,
                                    float& mu, float& rstd) {
    float s = 0.f, ss = 0.f;
#pragma unroll
    for (int i = 0; i < NSLOT; i++) { s += st[2 * i]; ss += st[2 * i + 1]; }
    mu = s * (1.f / CNTF);
    const float var = ss * (1.f / CNTF) - mu * mu;
    rstd = rsqrtf(var + EPSV);
}

// ---------------------------------------------------------------------------
// MFMA GEMM, no LDS: X [B][T][K] bf16 c-contiguous (A-operand, rows = t),
// W [M][K] bf16 row-major (B-operand, cols = c_out). Block tile 128t x 128c,
// 4 waves (2x2 of 64x64), 16x16x32 MFMA, frags streamed from L2/L3.
// D lane map: col = lane&15, row = quad*4 + reg.
// ---------------------------------------------------------------------------
template <int KDIM, int EP>
__global__ __launch_bounds__(256, 2) void mm_k(
    const unsigned short* __restrict__ X,
    const unsigned short* __restrict__ W0,
    const unsigned short* __restrict__ W1p,
    const float* __restrict__ bias0, const float* __restrict__ bias1,
    const float* __restrict__ uv0,   const float* __restrict__ uv1,
    float* __restrict__ O_f32, unsigned short* __restrict__ O_bf,
    float* __restrict__ outAcc,
    const float* __restrict__ statsIn, float* __restrict__ statsOut,
    const float* __restrict__ alphaPtr, int Cout)
{
    const int b    = blockIdx.z;
    const int t0   = blockIdx.x * 128;
    const int lane = threadIdx.x & 63;
    const int wid  = threadIdx.x >> 6;
    const int wt   = wid & 1;
    const int wm   = wid >> 1;
    const int l15  = lane & 15;
    const int quad = lane >> 4;

    const unsigned short* W   = W0;
    const float* bias = bias0;
    const float* uv   = uv0;
    bool isRes = false;
    if (EP == EP_DUAL && blockIdx.y == 1) {
        W = W1p; bias = bias1; uv = uv1; isRes = true;
    }
    const int m0 = (EP == EP_DUAL) ? 0 : blockIdx.y * 128;

    const unsigned short* Xb =
        X + ((size_t)b * TLEN + t0 + wt * 64 + l15) * KDIM + quad * 8;
    const unsigned short* Wb =
        W + (size_t)(m0 + wm * 64 + l15) * KDIM + quad * 8;

    floatx4 acc[4][4];
#pragma unroll
    for (int i = 0; i < 4; i++)
#pragma unroll
        for (int j = 0; j < 4; j++)
#pragma unroll
            for (int r = 0; r < 4; r++) acc[i][j][r] = 0.f;

#pragma unroll 4
    for (int kc = 0; kc < KDIM / 32; ++kc) {
        const int ko = kc * 32;
        short8 a[4], w[4];
#pragma unroll
        for (int i = 0; i < 4; i++)
            a[i] = *reinterpret_cast<const short8*>(Xb + (size_t)i * 16 * KDIM + ko);
#pragma unroll
        for (int j = 0; j < 4; j++)
            w[j] = *reinterpret_cast<const short8*>(Wb + (size_t)j * 16 * KDIM + ko);
#pragma unroll
        for (int i = 0; i < 4; i++)
#pragma unroll
            for (int j = 0; j < 4; j++)
                acc[i][j] = __builtin_amdgcn_mfma_f32_16x16x32_bf16(
                    a[i], w[j], acc[i][j], 0, 0, 0);
    }

    float mu = 0.f, rstd = 1.f, alpha = 0.f;
    if (EP == EP_FIRST || EP == EP_DUAL)
        load_stats32(statsIn + b * (2 * NSLOT), mu, rstd);
    if (EP == EP_H) alpha = alphaPtr[0];

    float ssum = 0.f, ssq = 0.f;
#pragma unroll
    for (int j = 0; j < 4; j++) {
        const int c = m0 + wm * 64 + j * 16 + l15;
        float bz = 0.f, rb = 0.f;
        if (EP == EP_H) bz = bias[c];
        else            rb = bias[c] + uv[c] - mu * rstd * uv[c + Cout];
#pragma unroll
        for (int i = 0; i < 4; i++) {
            const int tb = t0 + wt * 64 + i * 16 + quad * 4;
#pragma unroll
            for (int r = 0; r < 4; r++) {
                float val = acc[i][j][r];
                const size_t idx = ((size_t)b * TLEN + tb + r) * Cout + c;
                if (EP == EP_H) {
                    val += bz;
                    val = val >= 0.f ? val : alpha * val;
                    ssum += val; ssq += val * val;
                    O_bf[idx] = f2bf(val);
                } else if (EP == EP_FIRST) {
                    val = rstd * val + rb;
                    O_f32[idx] = val;
                    O_bf[idx] = f2bf(val);
                } else {
                    val = rstd * val + rb;
                    if (!isRes) {
                        outAcc[idx] += val;
                    } else {
                        const float f = O_f32[idx] + val;
                        O_f32[idx] = f;
                        O_bf[idx] = f2bf(f);
                    }
                }
            }
        }
    }
    if (EP == EP_H)
        block_reduce_atomic2(ssum, ssq,
            statsOut + b * (2 * NSLOT) + ((blockIdx.x + blockIdx.y * 25) & (NSLOT - 1)) * 2);
}

// Final GEMM: out[b][m][t] = sigmoid(Wo @ PReLU(outAcc) + bo).
// A-operand = Wo (rows = m_out), B-operand = PReLU(outAcc) (cols = t).
__global__ __launch_bounds__(256, 2) void mm_final_k(
    const float* __restrict__ Xa, const unsigned short* __restrict__ Wb,
    const float* __restrict__ bo, const float* __restrict__ aoutPtr,
    float* __restrict__ out)
{
    const int b    = blockIdx.z;
    const int t0   = blockIdx.x * 128;
    const int m0   = blockIdx.y * 128;
    const int lane = threadIdx.x & 63;
    const int wid  = threadIdx.x >> 6;
    const int wc   = wid & 1;    // t half
    const int wr   = wid >> 1;   // m half
    const int l15  = lane & 15;
    const int quad = lane >> 4;
    const float alpha = aoutPtr[0];

    const unsigned short* Wp =
        Wb + (size_t)(m0 + wr * 64 + l15) * BCH + quad * 8;
    const float* Xp =
        Xa + ((size_t)b * TLEN + t0 + wc * 64 + l15) * BCH + quad * 8;

    floatx4 acc[4][4];
#pragma unroll
    for (int i = 0; i < 4; i++)
#pragma unroll
        for (int j = 0; j < 4; j++)
#pragma unroll
            for (int r = 0; r < 4; r++) acc[i][j][r] = 0.f;

#pragma unroll
    for (int kc = 0; kc < BCH / 32; ++kc) {
        const int ko = kc * 32;
        short8 a[4], x[4];
#pragma unroll
        for (int i = 0; i < 4; i++)
            a[i] = *reinterpret_cast<const short8*>(Wp + (size_t)i * 16 * BCH + ko);
#pragma unroll
        for (int j = 0; j < 4; j++) {
            const float* p = Xp + (size_t)j * 16 * BCH + ko;
            float4 v0 = *reinterpret_cast<const float4*>(p);
            float4 v1 = *reinterpret_cast<const float4*>(p + 4);
            float f[8] = { v0.x, v0.y, v0.z, v0.w, v1.x, v1.y, v1.z, v1.w };
            short8 s;
#pragma unroll
            for (int jj = 0; jj < 8; jj++) {
                const float pv = f[jj] >= 0.f ? f[jj] : alpha * f[jj];
                s[jj] = (short)f2bf(pv);
            }
            x[j] = s;
        }
#pragma unroll
        for (int i = 0; i < 4; i++)
#pragma unroll
            for (int j = 0; j < 4; j++)
                acc[i][j] = __builtin_amdgcn_mfma_f32_16x16x32_bf16(
                    a[i], x[j], acc[i][j], 0, 0, 0);
    }

#pragma unroll
    for (int i = 0; i < 4; i++) {
        const int mb = m0 + wr * 64 + i * 16 + quad * 4;
#pragma unroll
        for (int r = 0; r < 4; r++) {
            const int m = mb + r;
            const float bz = bo[m];
#pragma unroll
            for (int j = 0; j < 4; j++) {
                const int t = t0 + wc * 64 + j * 16 + l15;
                float val = acc[i][j][r] + bz;
                val = 1.f / (1.f + expf(-val));
                out[((size_t)b * (2 * NCH) + m) * TLEN + t] = val;
            }
        }
    }
}

// Weight prep: bf16 convert with optional per-column gLN gamma fold, plus
// u = W @ be, v = W @ g row-vectors. One wave per row.
__global__ __launch_bounds__(256) void prep_w_k(
    const float* __restrict__ W, const float* __restrict__ g,
    const float* __restrict__ be, unsigned short* __restrict__ Wout,
    float* __restrict__ uv, int Mrows, int K, int nmat)
{
    const int r    = blockIdx.x * 4 + (threadIdx.x >> 6);
    const int lane = threadIdx.x & 63;
    if (r >= Mrows * nmat) return;
    const int mat = r / Mrows;
    const int m   = r - mat * Mrows;
    const float* Wrow = W + (size_t)r * K;
    const float* gv = g  ? g  + (size_t)mat * K : nullptr;
    const float* bv = be ? be + (size_t)mat * K : nullptr;
    float u = 0.f, v = 0.f;
    for (int k = lane * 4; k < K; k += 256) {
        float4 w4 = *reinterpret_cast<const float4*>(Wrow + k);
        float4 o4 = w4;
        if (gv) {
            const float4 g4 = *reinterpret_cast<const float4*>(gv + k);
            const float4 b4 = *reinterpret_cast<const float4*>(bv + k);
            o4.x = w4.x * g4.x; o4.y = w4.y * g4.y;
            o4.z = w4.z * g4.z; o4.w = w4.w * g4.w;
            u += w4.x * b4.x + w4.y * b4.y + w4.z * b4.z + w4.w * b4.w;
            v += w4.x * g4.x + w4.y * g4.y + w4.z * g4.z + w4.w * g4.w;
        }
        short4v s;
        s[0] = (short)f2bf(o4.x); s[1] = (short)f2bf(o4.y);
        s[2] = (short)f2bf(o4.z); s[3] = (short)f2bf(o4.w);
        *reinterpret_cast<short4v*>(Wout + (size_t)r * K + k) = s;
    }
    if (gv && uv) {
#pragma unroll
        for (int off = 32; off; off >>= 1) {
            u += __shfl_down(u, off, 64);
            v += __shfl_down(v, off, 64);
        }
        if (lane == 0) {
            uv[(size_t)mat * 2 * Mrows + m]         = u;
            uv[(size_t)mat * 2 * Mrows + Mrows + m] = v;
        }
    }
}

// Transpose + bf16 cvt: x [b][512][3200] fp32 -> x_t [b][3200][512] bf16.
__global__ __launch_bounds__(256) void tr_x_k(
    const float* __restrict__ x, unsigned short* __restrict__ xt)
{
    __shared__ unsigned short tile[32][33];
    const int b  = blockIdx.z;
    const int t0 = blockIdx.x * 32;
    const int c0 = blockIdx.y * 32;
#pragma unroll
    for (int r = 0; r < 4; r++) {
        const int cl = threadIdx.y + r * 8;
        tile[threadIdx.x][cl] =
            f2bf(x[((size_t)b * NCH + c0 + cl) * TLEN + t0 + threadIdx.x]);
    }
    __syncthreads();
#pragma unroll
    for (int r = 0; r < 4; r++) {
        const int tl = threadIdx.y + r * 8;
        xt[((size_t)b * TLEN + t0 + tl) * NCH + c0 + threadIdx.x] =
            tile[tl][threadIdx.x];
    }
}

// Depthwise dilated conv on [b][t][c] bf16, gLN(g1,be1) folded per tap,
// + bd, PReLU(a2), stats of result.
__global__ __launch_bounds__(256) void dwconv_k(
    const unsigned short* __restrict__ h, unsigned short* __restrict__ hd,
    const float* __restrict__ Wd, const float* __restrict__ bd,
    const float* __restrict__ g1, const float* __restrict__ be1,
    const float* __restrict__ statsIn, float* __restrict__ statsOut,
    const float* __restrict__ a2p, int dil)
{
    const int b  = blockIdx.y;
    const int t  = blockIdx.x * 4 + (threadIdx.x >> 6);
    const int c0 = (threadIdx.x & 63) * 8;

    float mu, rstd;
    load_stats32(statsIn + b * (2 * NSLOT), mu, rstd);
    const float alpha = a2p[0];

    float g[8], be[8], bz[8], wall[24];
#pragma unroll
    for (int q = 0; q < 6; q++) {
        const float4 w4 = *reinterpret_cast<const float4*>(Wd + (size_t)c0 * 3 + q * 4);
        wall[q * 4 + 0] = w4.x; wall[q * 4 + 1] = w4.y;
        wall[q * 4 + 2] = w4.z; wall[q * 4 + 3] = w4.w;
    }
    {
        const float4 ga = *reinterpret_cast<const float4*>(g1 + c0);
        const float4 gb = *reinterpret_cast<const float4*>(g1 + c0 + 4);
        const float4 ba = *reinterpret_cast<const float4*>(be1 + c0);
        const float4 bb = *reinterpret_cast<const float4*>(be1 + c0 + 4);
        const float4 da = *reinterpret_cast<const float4*>(bd + c0);
        const float4 db = *reinterpret_cast<const float4*>(bd + c0 + 4);
        const float gg[8] = { ga.x, ga.y, ga.z, ga.w, gb.x, gb.y, gb.z, gb.w };
        const float bbv[8] = { ba.x, ba.y, ba.z, ba.w, bb.x, bb.y, bb.z, bb.w };
        const float dd[8] = { da.x, da.y, da.z, da.w, db.x, db.y, db.z, db.w };
#pragma unroll
        for (int jj = 0; jj < 8; jj++) {
            g[jj]  = gg[jj] * rstd;
            be[jj] = bbv[jj] - mu * rstd * gg[jj];
            bz[jj] = dd[jj];
        }
    }

    const size_t rowb = ((size_t)b * TLEN + t) * HCH + c0;
    const bool hasP = (t - dil) >= 0;
    const bool hasN = (t + dil) < TLEN;
    const short8 cur = *reinterpret_cast<const short8*>(h + rowb);
    short8 prv = {}, nxt = {};
    if (hasP) prv = *reinterpret_cast<const short8*>(h + rowb - (size_t)dil * HCH);
    if (hasN) nxt = *reinterpret_cast<const short8*>(h + rowb + (size_t)dil * HCH);

    float psum = 0.f, psq = 0.f;
    short8 o;
#pragma unroll
    for (int jj = 0; jj < 8; jj++) {
        float acc = bz[jj] + wall[jj * 3 + 1] * (g[jj] * bf2f(cur[jj]) + be[jj]);
        if (hasP) acc += wall[jj * 3 + 0] * (g[jj] * bf2f(prv[jj]) + be[jj]);
        if (hasN) acc += wall[jj * 3 + 2] * (g[jj] * bf2f(nxt[jj]) + be[jj]);
        const float v = acc >= 0.f ? acc : alpha * acc;
        o[jj] = (short)f2bf(v);
        psum += v; psq += v * v;
    }
    *reinterpret_cast<short8*>(hd + rowb) = o;
    block_reduce_atomic2(psum, psq,
        statsOut + b * (2 * NSLOT) + (blockIdx.x & (NSLOT - 1)) * 2);
}

__global__ __launch_bounds__(256) void stats_x_k(
    const float* __restrict__ x, float* __restrict__ statsOut)
{
    const int b = blockIdx.y;
    const float* base = x + (size_t)b * (NCH * TLEN) + (size_t)blockIdx.x * 16384;
    float s = 0.f, ss = 0.f;
#pragma unroll
    for (int i = 0; i < 16; i++) {
        const float4 v = *reinterpret_cast<const float4*>(base + i * 1024 + threadIdx.x * 4);
        s  += v.x + v.y + v.z + v.w;
        ss += v.x * v.x + v.y * v.y + v.z * v.z + v.w * v.w;
    }
    block_reduce_atomic2(s, ss,
        statsOut + b * (2 * NSLOT) + (blockIdx.x & (NSLOT - 1)) * 2);
}

extern "C" void kernel_launch(void* const* d_in, const int* in_sizes, int n_in,
                              void* d_out, int out_size, void* d_ws, size_t ws_size,
                              hipStream_t stream)
{
    (void)in_sizes; (void)n_in; (void)out_size; (void)ws_size;

    const float* x    = (const float*)d_in[0];
    const float* in_g = (const float*)d_in[1];
    const float* in_b = (const float*)d_in[2];
    const float* Wc   = (const float*)d_in[3];
    const float* bc   = (const float*)d_in[4];
    const float* W1   = (const float*)d_in[5];
    const float* b1   = (const float*)d_in[6];
    const float* a1   = (const float*)d_in[7];
    const float* g1   = (const float*)d_in[8];
    const float* be1  = (const float*)d_in[9];
    const float* Wd   = (const float*)d_in[10];
    const float* bd   = (const float*)d_in[11];
    const float* a2   = (const float*)d_in[12];
    const float* g2   = (const float*)d_in[13];
    const float* be2  = (const float*)d_in[14];
    const float* Wres = (const float*)d_in[15];
    const float* bres = (const float*)d_in[16];
    const float* Wskip= (const float*)d_in[17];
    const float* bskip= (const float*)d_in[18];
    const float* aout = (const float*)d_in[19];
    const float* Wo   = (const float*)d_in[20];
    const float* bo   = (const float*)d_in[21];
    float* out = (float*)d_out;

    // workspace carve-up (bytes, 16B-aligned regions)
    uint8_t* p = (uint8_t*)d_ws;
    unsigned short* x_t      = (unsigned short*)p; p += (size_t)BATCHN*TLEN*NCH*2;
    float*          feats    = (float*)p;          p += (size_t)BATCHN*TLEN*BCH*4;
    unsigned short* feats_bf = (unsigned short*)p; p += (size_t)BATCHN*TLEN*BCH*2;
    float*          outAcc   = (float*)p;          p += (size_t)BATCHN*TLEN*BCH*4;
    unsigned short* h        = (unsigned short*)p; p += (size_t)BATCHN*TLEN*HCH*2;
    unsigned short* hd       = (unsigned short*)p; p += (size_t)BATCHN*TLEN*HCH*2;
    unsigned short* WcG      = (unsigned short*)p; p += (size_t)BCH*NCH*2;
    unsigned short* W1b      = (unsigned short*)p; p += (size_t)LBLK*HCH*BCH*2;
    unsigned short* WsG      = (unsigned short*)p; p += (size_t)LBLK*BCH*HCH*2;
    unsigned short* WrG      = (unsigned short*)p; p += (size_t)(LBLK-1)*BCH*HCH*2;
    unsigned short* Wob      = (unsigned short*)p; p += (size_t)(2*NCH)*BCH*2;
    float*          uv_c     = (float*)p;          p += (size_t)2*BCH*4;
    float*          uv_s     = (float*)p;          p += (size_t)LBLK*2*BCH*4;
    float*          uv_r     = (float*)p;          p += (size_t)(LBLK-1)*2*BCH*4;
    float*          stats    = (float*)p;

    const size_t SLOTF = (size_t)BATCHN * 2 * NSLOT;  // floats per stat slot

    hipMemsetAsync(stats, 0, (size_t)49 * SLOTF * sizeof(float), stream);
    hipMemsetAsync(outAcc, 0, (size_t)BATCHN*TLEN*BCH*sizeof(float), stream);

    // ---- prep ----
    stats_x_k<<<dim3(100, BATCHN), 256, 0, stream>>>(x, stats);
    tr_x_k<<<dim3(100, 16, BATCHN), dim3(32, 8), 0, stream>>>(x, x_t);
    prep_w_k<<<32,   256, 0, stream>>>(Wc,   in_g,    in_b,    WcG, uv_c, BCH,   NCH, 1);
    prep_w_k<<<3072, 256, 0, stream>>>(W1,   nullptr, nullptr, W1b, nullptr, HCH, BCH, LBLK);
    prep_w_k<<<768,  256, 0, stream>>>(Wskip,g2,      be2,     WsG, uv_s, BCH,   HCH, LBLK);
    prep_w_k<<<736,  256, 0, stream>>>(Wres, g2,      be2,     WrG, uv_r, BCH,   HCH, LBLK-1);
    prep_w_k<<<256,  256, 0, stream>>>(Wo,   nullptr, nullptr, Wob, nullptr, 2*NCH, BCH, 1);

    // ---- first: feats = rstd*(WcG @ x_t) + rowbias ----
    mm_k<NCH, EP_FIRST><<<dim3(25, 1, BATCHN), 256, 0, stream>>>(
        x_t, WcG, nullptr, bc, nullptr, uv_c, nullptr,
        feats, feats_bf, nullptr, stats, nullptr, nullptr, BCH);

    for (int i = 0; i < LBLK; i++) {
        const int dil = 1 << (i & 7);
        float* st_h  = stats + (size_t)(1 + 2 * i) * SLOTF;
        float* st_hd = stats + (size_t)(2 + 2 * i) * SLOTF;

        mm_k<BCH, EP_H><<<dim3(25, 4, BATCHN), 256, 0, stream>>>(
            feats_bf, W1b + (size_t)i * HCH * BCH, nullptr,
            b1 + (size_t)i * HCH, nullptr, nullptr, nullptr,
            nullptr, h, nullptr, nullptr, st_h, a1 + i, HCH);

        dwconv_k<<<dim3(TLEN / 4, BATCHN), 256, 0, stream>>>(
            h, hd, Wd + (size_t)i * HCH * 3, bd + (size_t)i * HCH,
            g1 + (size_t)i * HCH, be1 + (size_t)i * HCH,
            st_h, st_hd, a2 + i, dil);

        const int mt = (i < LBLK - 1) ? 2 : 1;
        mm_k<HCH, EP_DUAL><<<dim3(25, mt, BATCHN), 256, 0, stream>>>(
            hd, WsG + (size_t)i * BCH * HCH, WrG + (size_t)i * BCH * HCH,
            bskip + (size_t)i * BCH, bres + (size_t)i * BCH,
            uv_s + (size_t)i * 2 * BCH, uv_r + (size_t)i * 2 * BCH,
            feats, feats_bf, outAcc, st_hd, nullptr, nullptr, BCH);
    }

    mm_final_k<<<dim3(25, 8, BATCHN), 256, 0, stream>>>(
        outAcc, Wob, bo, aout, out);
}